// Round 1
// baseline (174.153 us; speedup 1.0000x reference)
//
#include <hip/hip_runtime.h>

// Problem constants
constexpr int IN_C  = 256;
constexpr int MID   = 32;
constexpr int OUT_C = 128;
constexpr int NR    = 512;
constexpr int NL    = 256;
constexpr int M     = 4;
constexpr long ROW_STRIDE = (long)(NR + NL) * OUT_C;   // 768*128 = 98304

// Workspace layout (float offsets)
constexpr long WS_PR4 = 0;                              // [4][512][32]   = 65536
constexpr long WS_PL4 = WS_PR4 + 4L * NR * MID;         // [4][4][256][32]= 131072
constexpr long WS_PLM = WS_PL4 + 4L * M * NL * MID;     // [2][256][32]   = 16384
constexpr long WS_LLL = WS_PLM + 2L * NL * MID;         // [256][128]     = 32768
constexpr long WS_TRR = WS_LLL + (long)NL * M * MID;    // [512][32*128]  = 2097152
constexpr long WS_TRL = WS_TRR + (long)NR * MID * OUT_C;// [256][32*128]  = 1048576
constexpr long WS_TLR = WS_TRL + (long)NL * MID * OUT_C;// [256][32*128]  = 1048576
constexpr long WS_TLL = WS_TLR + (long)NL * MID * OUT_C;// [256][128*128] = 4194304

__device__ inline void fma4(float4& a, float s, const float4& t) {
    a.x += s * t.x; a.y += s * t.y; a.z += s * t.z; a.w += s * t.w;
}

// ---------------------------------------------------------------------------
// K1: LayerNorm + projection. One block per row (512 rec rows + 1024 lig rows).
// Writes projections de-interleaved by chunk-slice: P4[s][row][x], s = c&3, x = c>>2
// ---------------------------------------------------------------------------
__global__ __launch_bounds__(256) void ln_proj_kernel(
    const float* __restrict__ rec, const float* __restrict__ lig,
    const float* __restrict__ rg, const float* __restrict__ rb,
    const float* __restrict__ lg, const float* __restrict__ lb,
    const float* __restrict__ Wr, const float* __restrict__ br,
    const float* __restrict__ Wl, const float* __restrict__ bl,
    float* __restrict__ ws)
{
    int row = blockIdx.x;
    const float *X, *g, *bvec, *W, *bias;
    float* P4;
    long slice_stride;
    int prow;
    if (row < NR) {
        X = rec + (long)row * IN_C; g = rg; bvec = rb; W = Wr; bias = br;
        P4 = ws + WS_PR4; slice_stride = (long)NR * MID; prow = row;
    } else {
        int rl_ = row - NR;                       // m*256 + j
        X = lig + (long)rl_ * IN_C; g = lg; bvec = lb; W = Wl; bias = bl;
        P4 = ws + WS_PL4; slice_stride = (long)M * NL * MID; prow = rl_;
    }

    __shared__ __align__(16) float xn[IN_C];
    __shared__ float red[8];
    __shared__ float musig[2];
    __shared__ float part[256];

    int tid = threadIdx.x;
    float x = X[tid];
    float s = x, s2 = x * x;
    #pragma unroll
    for (int off = 32; off > 0; off >>= 1) {
        s  += __shfl_down(s,  off, 64);
        s2 += __shfl_down(s2, off, 64);
    }
    int wid = tid >> 6;
    if ((tid & 63) == 0) { red[wid] = s; red[4 + wid] = s2; }
    __syncthreads();
    if (tid == 0) {
        float sum  = red[0] + red[1] + red[2] + red[3];
        float sum2 = red[4] + red[5] + red[6] + red[7];
        float mu  = sum * (1.f / IN_C);
        float var = sum2 * (1.f / IN_C) - mu * mu;
        musig[0] = mu;
        musig[1] = rsqrtf(var + 1e-5f);
    }
    __syncthreads();
    float mu = musig[0], rs = musig[1];
    xn[tid] = (x - mu) * rs * g[tid] + bvec[tid];
    __syncthreads();

    // projection: 128 outputs, 2 threads each (half dots)
    int c = tid & 127, h = tid >> 7;
    const float* wrow = W + (long)c * IN_C + h * 128;
    const float* xp   = xn + h * 128;
    float acc = 0.f;
    #pragma unroll
    for (int k = 0; k < 128; k += 4) {
        float4 w4 = *(const float4*)(wrow + k);
        float4 x4 = *(const float4*)(xp + k);
        acc += w4.x * x4.x + w4.y * x4.y + w4.z * x4.z + w4.w * x4.w;
    }
    part[tid] = acc;
    __syncthreads();
    if (tid < 128) {
        float val = part[tid] + part[tid + 128] + bias[tid];
        int slice = tid & 3, xi = tid >> 2;
        P4[(long)slice * slice_stride + (long)prow * MID + xi] = val;
    }
}

// ---------------------------------------------------------------------------
// K2: ligand means over m (for rl/lr), and L_ll gather [i][m*32+x]
// ---------------------------------------------------------------------------
__global__ __launch_bounds__(256) void means_kernel(float* __restrict__ ws)
{
    int idx = blockIdx.x * 256 + threadIdx.x;
    const float* pl4 = ws + WS_PL4;
    if (idx < 2 * NL * MID) {                     // 16384: plm[s][j][x]
        int s = idx >> 13;                        // 8192 = 256*32
        int r = idx & 8191;
        float v = 0.25f * (pl4[(long)s * 32768 + 0 * 8192 + r] +
                           pl4[(long)s * 32768 + 1 * 8192 + r] +
                           pl4[(long)s * 32768 + 2 * 8192 + r] +
                           pl4[(long)s * 32768 + 3 * 8192 + r]);
        ws[WS_PLM + idx] = v;
    } else {
        int id2 = idx - 16384;                    // < 32768: L_ll[i][m*32+x]
        int i = id2 >> 7, k = id2 & 127;
        int m = k >> 5, xx = k & 31;
        ws[WS_LLL + id2] = pl4[2L * 32768 + (long)m * 8192 + (long)i * 32 + xx];
    }
}

// ---------------------------------------------------------------------------
// K3: t-tensors. T[j][x*128+o] = scale * sum_y W[o,x,y] * V[j,y]
// Block = (j-tile of 32) x (column chunk of 1024). 256 blocks total.
// ll mode: j' = m*256+j, write at [j][(m*32+x)*128+o]
// ---------------------------------------------------------------------------
__global__ __launch_bounds__(256) void build_t_kernel(
    const float* __restrict__ Wrr, const float* __restrict__ Wrl,
    const float* __restrict__ Wlr, const float* __restrict__ Wll,
    float* __restrict__ ws)
{
    int bid = blockIdx.x;
    const float *W, *V;
    float* T;
    float scale = 1.f;
    bool llm = false;
    int rb;
    if (bid < 64)       { W = Wrr; V = ws + WS_PR4 + 16384;   T = ws + WS_TRR; rb = bid; }
    else if (bid < 96)  { W = Wrl; V = ws + WS_PLM + 8192;    T = ws + WS_TRL; rb = bid - 64; }
    else if (bid < 128) { W = Wlr; V = ws + WS_PLM;           T = ws + WS_TLR; rb = bid - 96; }
    else                { W = Wll; V = ws + WS_PL4 + 3 * 32768; T = ws + WS_TLL; rb = bid - 128; scale = 0.25f; llm = true; }

    int cc = rb & 3, jt = rb >> 2;
    int j0 = jt * 32;
    __shared__ __align__(16) float v[32][32];
    int tid = threadIdx.x;
    #pragma unroll
    for (int q = 0; q < 4; ++q) {
        int f = tid + q * 256;
        v[f >> 5][f & 31] = V[(long)j0 * 32 + f];
    }
    __syncthreads();

    #pragma unroll
    for (int pp = 0; pp < 2; ++pp) {
        int colA = cc * 1024 + (pp * 2) * 256 + tid;
        int colB = colA + 256;
        float wa[32], wb[32];
        {
            int oA = colA & 127, xA = colA >> 7;
            int oB = colB & 127, xB = colB >> 7;
            const float4* wpA = (const float4*)(W + (long)oA * 1024 + xA * 32);
            const float4* wpB = (const float4*)(W + (long)oB * 1024 + xB * 32);
            #pragma unroll
            for (int t4 = 0; t4 < 8; ++t4) {
                ((float4*)wa)[t4] = wpA[t4];
                ((float4*)wb)[t4] = wpB[t4];
            }
        }
        for (int jl = 0; jl < 32; ++jl) {
            float accA = 0.f, accB = 0.f;
            #pragma unroll
            for (int y4 = 0; y4 < 8; ++y4) {
                float4 vv = *(const float4*)&v[jl][y4 * 4];
                accA += wa[y4*4+0]*vv.x + wa[y4*4+1]*vv.y + wa[y4*4+2]*vv.z + wa[y4*4+3]*vv.w;
                accB += wb[y4*4+0]*vv.x + wb[y4*4+1]*vv.y + wb[y4*4+2]*vv.z + wb[y4*4+3]*vv.w;
            }
            int j = j0 + jl;
            long base = llm ? ((long)(j & 255) * 16384 + (long)(j >> 8) * 4096)
                            : ((long)j * 4096);
            T[base + colA] = accA * scale;
            T[base + colB] = accB * scale;
        }
    }
}

// ---------------------------------------------------------------------------
// K4: epilogue. out(i,j,o) = bias[o] + sum_k L[i,k] * T[j,k*128+o]
// Block = one j x 32-row i-tile. 256 thr: 32 o-groups (float4) x 8 i-groups x 4 i.
// XCD-aware swizzle: all i-tiles of a j land on one XCD.
// ---------------------------------------------------------------------------
__global__ __launch_bounds__(256) void epilogue_kernel(
    const float* __restrict__ ws, float* __restrict__ out,
    const float* __restrict__ brr, const float* __restrict__ brl,
    const float* __restrict__ blr, const float* __restrict__ bll)
{
    int bid = blockIdx.x;
    const float *L, *T, *bias;
    float* ob;
    long istr, jstr;
    int K, nTilesI, rb;
    if (bid < 8192) {        // rr
        rb = bid;          L = ws + WS_PR4;             T = ws + WS_TRR; bias = brr;
        ob = out;                                        istr = ROW_STRIDE; jstr = 128; K = 32;  nTilesI = 16;
    } else if (bid < 12288) { // rl
        rb = bid - 8192;   L = ws + WS_PR4 + 2 * 16384; T = ws + WS_TRL; bias = brl;
        ob = out + (long)NR * OUT_C;                     istr = ROW_STRIDE; jstr = 128; K = 32;  nTilesI = 16;
    } else if (bid < 16384) { // lr (i = rec along columns, j = lig along rows)
        rb = bid - 12288;  L = ws + WS_PR4 + 3 * 16384; T = ws + WS_TLR; bias = blr;
        ob = out + (long)NR * ROW_STRIDE;                istr = 128; jstr = ROW_STRIDE; K = 32;  nTilesI = 16;
    } else {                  // ll
        rb = bid - 16384;  L = ws + WS_LLL;             T = ws + WS_TLL; bias = bll;
        ob = out + (long)NR * ROW_STRIDE + (long)NR * OUT_C; istr = ROW_STRIDE; jstr = 128; K = 128; nTilesI = 8;
    }

    int xcd = rb & 7, r = rb >> 3;
    int it  = r % nTilesI;
    int j   = (r / nTilesI) * 8 + xcd;
    int i0  = it * 32;

    __shared__ __align__(16) float t_lds[4096];
    __shared__ __align__(16) float l_lds[4096];
    int tid = threadIdx.x;

    { // stage L tile: 32 rows x K
        const float4* src = (const float4*)(L + (long)i0 * K);
        float4* dst = (float4*)l_lds;
        int n4 = (32 * K) >> 2;
        for (int f = tid; f < n4; f += 256) dst[f] = src[f];
    }

    int og = tid & 31, ig = tid >> 5;
    int o4 = og * 4;
    float4 bb = *(const float4*)(bias + o4);
    float4 acc0 = bb, acc1 = bb, acc2 = bb, acc3 = bb;

    const float4* tsrc = (const float4*)(T + (long)j * K * 128);
    const float* l0p = l_lds + (long)(ig)      * K;
    const float* l1p = l_lds + (long)(ig + 8)  * K;
    const float* l2p = l_lds + (long)(ig + 16) * K;
    const float* l3p = l_lds + (long)(ig + 24) * K;

    int nkt = K >> 5;
    for (int kt = 0; kt < nkt; ++kt) {
        __syncthreads();
        { // stage T k-tile: [32 k][128 o] = 4096 floats
            float4* tdst = (float4*)t_lds;
            #pragma unroll
            for (int f = 0; f < 4; ++f)
                tdst[tid + f * 256] = tsrc[(long)kt * 1024 + tid + f * 256];
        }
        __syncthreads();
        int kb = kt * 32;
        #pragma unroll
        for (int k4 = 0; k4 < 32; k4 += 4) {
            float4 l0 = *(const float4*)(l0p + kb + k4);
            float4 l1 = *(const float4*)(l1p + kb + k4);
            float4 l2 = *(const float4*)(l2p + kb + k4);
            float4 l3 = *(const float4*)(l3p + kb + k4);
            const float* f0 = (const float*)&l0;
            const float* f1 = (const float*)&l1;
            const float* f2 = (const float*)&l2;
            const float* f3 = (const float*)&l3;
            #pragma unroll
            for (int kk = 0; kk < 4; ++kk) {
                float4 t4 = *(const float4*)&t_lds[(k4 + kk) * 128 + o4];
                fma4(acc0, f0[kk], t4);
                fma4(acc1, f1[kk], t4);
                fma4(acc2, f2[kk], t4);
                fma4(acc3, f3[kk], t4);
            }
        }
    }

    float* obase = ob + (long)j * jstr + o4;
    *(float4*)(obase + (long)(i0 + ig)      * istr) = acc0;
    *(float4*)(obase + (long)(i0 + ig + 8)  * istr) = acc1;
    *(float4*)(obase + (long)(i0 + ig + 16) * istr) = acc2;
    *(float4*)(obase + (long)(i0 + ig + 24) * istr) = acc3;
}

extern "C" void kernel_launch(void* const* d_in, const int* in_sizes, int n_in,
                              void* d_out, int out_size, void* d_ws, size_t ws_size,
                              hipStream_t stream)
{
    (void)in_sizes; (void)n_in; (void)out_size; (void)ws_size;
    const float* rec = (const float*)d_in[0];
    const float* lig = (const float*)d_in[1];
    // d_in[2] = pw_rep: shape-only, never read (all 4 quadrants are overwritten)
    const float* rg  = (const float*)d_in[3];
    const float* rb  = (const float*)d_in[4];
    const float* lg  = (const float*)d_in[5];
    const float* lb  = (const float*)d_in[6];
    const float* Wr  = (const float*)d_in[7];
    const float* br  = (const float*)d_in[8];
    const float* Wl  = (const float*)d_in[9];
    const float* bl  = (const float*)d_in[10];
    const float* Wrr = (const float*)d_in[11];
    const float* brr = (const float*)d_in[12];
    const float* Wrl = (const float*)d_in[13];
    const float* brl = (const float*)d_in[14];
    const float* Wlr = (const float*)d_in[15];
    const float* blr = (const float*)d_in[16];
    const float* Wll = (const float*)d_in[17];
    const float* bll = (const float*)d_in[18];
    float* out = (float*)d_out;
    float* ws  = (float*)d_ws;

    hipLaunchKernelGGL(ln_proj_kernel, dim3(NR + M * NL), dim3(256), 0, stream,
                       rec, lig, rg, rb, lg, lb, Wr, br, Wl, bl, ws);
    hipLaunchKernelGGL(means_kernel, dim3(192), dim3(256), 0, stream, ws);
    hipLaunchKernelGGL(build_t_kernel, dim3(256), dim3(256), 0, stream,
                       Wrr, Wrl, Wlr, Wll, ws);
    hipLaunchKernelGGL(epilogue_kernel, dim3(18432), dim3(256), 0, stream,
                       ws, out, brr, brl, blr, bll);
}

// Round 2
// 147.063 us; speedup vs baseline: 1.1842x; 1.1842x over previous
//
#include <hip/hip_runtime.h>

// Problem constants
constexpr int IN_C  = 256;
constexpr int MID   = 32;
constexpr int OUT_C = 128;
constexpr int NR    = 512;
constexpr int NL    = 256;
constexpr int M     = 4;
constexpr long ROW_STRIDE = (long)(NR + NL) * OUT_C;   // 768*128 = 98304

// ---- workspace layout ----
// f32 region (float offsets)
constexpr long WS_PR4 = 0;                               // [4][512][32]   (rec proj, slice-major)
constexpr long WS_PL4 = WS_PR4 + 4L * NR * MID;          // [4][4][256][32] (lig proj [s][m][j][y])
constexpr long WS_F32_END = WS_PL4 + 4L * M * NL * MID;  // 196608 floats
// bf16 region (ushort offsets into ws)
constexpr long BF_LRR = 2 * WS_F32_END;                  // [512][32]  r_ri
constexpr long BF_LRL = BF_LRR + (long)NR * MID;         // [512][32]  r_li
constexpr long BF_LLR = BF_LRL + (long)NR * MID;         // [512][32]  r_lj
constexpr long BF_LLL = BF_LLR + (long)NR * MID;         // [256][128] l_li gathered [i][m*32+x]
constexpr long BF_TRR = BF_LLL + (long)NL * M * MID;     // [512][128][32]  T[j][o][k]
constexpr long BF_TRL = BF_TRR + (long)NR * OUT_C * MID; // [256][128][32]
constexpr long BF_TLR = BF_TRL + (long)NL * OUT_C * MID; // [256][128][32]
constexpr long BF_TLL = BF_TLR + (long)NL * OUT_C * MID; // [256][128][128]

typedef __bf16 bf16x8 __attribute__((ext_vector_type(8)));
typedef float  f32x4  __attribute__((ext_vector_type(4)));

__device__ inline unsigned short f2bf(float f) {
    unsigned int u = __float_as_uint(f);
    u = (u + 0x7fffu + ((u >> 16) & 1u)) >> 16;   // round-to-nearest-even
    return (unsigned short)u;
}

// ---------------------------------------------------------------------------
// K1: LayerNorm + projection. One block per row (512 rec + 1024 lig rows).
// f32 slices P4[s][row][x] for T-build inputs; bf16 L arrays for the MFMA epilogue.
// ---------------------------------------------------------------------------
__global__ __launch_bounds__(256) void ln_proj_kernel(
    const float* __restrict__ rec, const float* __restrict__ lig,
    const float* __restrict__ rg, const float* __restrict__ rb,
    const float* __restrict__ lg, const float* __restrict__ lb,
    const float* __restrict__ Wr, const float* __restrict__ br,
    const float* __restrict__ Wl, const float* __restrict__ bl,
    float* __restrict__ ws)
{
    int row = blockIdx.x;
    bool isRec = (row < NR);
    const float *X, *g, *bvec, *W, *bias;
    float* P4;
    long slice_stride;
    int prow;
    if (isRec) {
        X = rec + (long)row * IN_C; g = rg; bvec = rb; W = Wr; bias = br;
        P4 = ws + WS_PR4; slice_stride = (long)NR * MID; prow = row;
    } else {
        int rl_ = row - NR;                       // m*256 + j
        X = lig + (long)rl_ * IN_C; g = lg; bvec = lb; W = Wl; bias = bl;
        P4 = ws + WS_PL4; slice_stride = (long)M * NL * MID; prow = rl_;
    }

    __shared__ __align__(16) float xn[IN_C];
    __shared__ float red[8];
    __shared__ float musig[2];
    __shared__ float part[256];

    int tid = threadIdx.x;
    float x = X[tid];
    float s = x, s2 = x * x;
    #pragma unroll
    for (int off = 32; off > 0; off >>= 1) {
        s  += __shfl_down(s,  off, 64);
        s2 += __shfl_down(s2, off, 64);
    }
    int wid = tid >> 6;
    if ((tid & 63) == 0) { red[wid] = s; red[4 + wid] = s2; }
    __syncthreads();
    if (tid == 0) {
        float sum  = red[0] + red[1] + red[2] + red[3];
        float sum2 = red[4] + red[5] + red[6] + red[7];
        float mu  = sum * (1.f / IN_C);
        float var = sum2 * (1.f / IN_C) - mu * mu;
        musig[0] = mu;
        musig[1] = rsqrtf(var + 1e-5f);
    }
    __syncthreads();
    float mu = musig[0], rs = musig[1];
    xn[tid] = (x - mu) * rs * g[tid] + bvec[tid];
    __syncthreads();

    // projection: 128 outputs, 2 threads each (half dots)
    int c = tid & 127, h = tid >> 7;
    const float* wrow = W + (long)c * IN_C + h * 128;
    const float* xp   = xn + h * 128;
    float acc = 0.f;
    #pragma unroll
    for (int k = 0; k < 128; k += 4) {
        float4 w4 = *(const float4*)(wrow + k);
        float4 x4 = *(const float4*)(xp + k);
        acc += w4.x * x4.x + w4.y * x4.y + w4.z * x4.z + w4.w * x4.w;
    }
    part[tid] = acc;
    __syncthreads();
    if (tid < 128) {
        float val = part[tid] + part[tid + 128] + bias[tid];
        int slice = tid & 3, xi = tid >> 2;
        P4[(long)slice * slice_stride + (long)prow * MID + xi] = val;

        unsigned short hb = f2bf(val);
        unsigned short* wsb = (unsigned short*)ws;
        if (isRec) {
            if (slice == 0)      wsb[BF_LRR + (long)prow * 32 + xi] = hb;   // r_ri
            else if (slice == 2) wsb[BF_LRL + (long)prow * 32 + xi] = hb;   // r_li
            else if (slice == 3) wsb[BF_LLR + (long)prow * 32 + xi] = hb;   // r_lj
        } else {
            if (slice == 2)      // l_li -> L_ll[i][m*32+x]
                wsb[BF_LLL + (long)(prow & 255) * 128 + (prow >> 8) * 32 + xi] = hb;
        }
    }
}

// ---------------------------------------------------------------------------
// K3: T[j][o][k] (bf16) = scale * sum_y W[o,x,y] * V[j,y]   (k = x, or m*32+x for ll)
// Means over m for rl/lr are computed inline while staging V.
// Block = (quadrant, j-tile of 32, column chunk of 1024 (o,x) pairs).
// Thread handles two adjacent x for one o -> packed 4-byte coalesced bf16 writes.
// ---------------------------------------------------------------------------
__global__ __launch_bounds__(256) void build_t_kernel(
    const float* __restrict__ Wrr, const float* __restrict__ Wrl,
    const float* __restrict__ Wlr, const float* __restrict__ Wll,
    float* __restrict__ ws)
{
    unsigned short* wsb = (unsigned short*)ws;
    const float* V4 = ws + WS_PL4;   // [s][m][j][y]
    int bid = blockIdx.x;
    const float* W;
    unsigned short* T;
    float scale = 1.f;
    int mode, jt, cc, mm = 0, K;
    if (bid < 64)       { mode = 0; W = Wrr; T = wsb + BF_TRR; int r = bid;       jt = r >> 2; cc = r & 3; K = 32; }
    else if (bid < 96)  { mode = 1; W = Wrl; T = wsb + BF_TRL; int r = bid - 64;  jt = r >> 2; cc = r & 3; K = 32; }
    else if (bid < 128) { mode = 2; W = Wlr; T = wsb + BF_TLR; int r = bid - 96;  jt = r >> 2; cc = r & 3; K = 32; }
    else                { mode = 3; W = Wll; T = wsb + BF_TLL; int r = bid - 128; mm = r >> 5; r &= 31;
                          jt = r >> 2; cc = r & 3; K = 128; scale = 0.25f; }
    int j0 = jt * 32;

    __shared__ __align__(16) float v[32][32];
    int tid = threadIdx.x;
    for (int f = tid; f < 1024; f += 256) {
        int jl = f >> 5, y = f & 31;
        float val;
        if (mode == 0) {
            val = ws[WS_PR4 + 1L * NR * MID + (long)(j0 + jl) * MID + y];        // r_rj
        } else if (mode == 3) {
            val = V4[3L * M * NL * MID + (long)mm * NL * MID + (long)(j0 + jl) * MID + y]; // l_lj[m]
        } else {
            int sl = (mode == 1) ? 1 : 0;                                        // l_rj / l_ri
            const float* p = V4 + (long)sl * M * NL * MID + (long)(j0 + jl) * MID + y;
            val = 0.25f * (p[0] + p[NL * MID] + p[2L * NL * MID] + p[3L * NL * MID]);
        }
        v[jl][y] = val;
    }
    __syncthreads();

    int koff = (mode == 3) ? mm * 32 : 0;
    long jstride = (long)K * 128;
    #pragma unroll
    for (int pp = 0; pp < 2; ++pp) {
        int cpair = cc * 1024 + pp * 512 + tid * 2;  // c = o*32 + x, x even
        int o = cpair >> 5, x = cpair & 31;
        float wa[32], wb[32];
        const float4* wp = (const float4*)(W + (long)o * 1024 + x * 32);
        #pragma unroll
        for (int t4 = 0; t4 < 8; ++t4) {
            ((float4*)wa)[t4] = wp[t4];
            ((float4*)wb)[t4] = wp[t4 + 8];
        }
        long obase = (long)o * K + koff + x;
        for (int jl = 0; jl < 32; ++jl) {
            float accA = 0.f, accB = 0.f;
            #pragma unroll
            for (int y4 = 0; y4 < 8; ++y4) {
                float4 vv = *(const float4*)&v[jl][y4 * 4];
                accA += wa[y4*4+0]*vv.x + wa[y4*4+1]*vv.y + wa[y4*4+2]*vv.z + wa[y4*4+3]*vv.w;
                accB += wb[y4*4+0]*vv.x + wb[y4*4+1]*vv.y + wb[y4*4+2]*vv.z + wb[y4*4+3]*vv.w;
            }
            unsigned int pk = (unsigned int)f2bf(accA * scale)
                            | ((unsigned int)f2bf(accB * scale) << 16);
            *(unsigned int*)(T + (long)(j0 + jl) * jstride + obase) = pk;
        }
    }
}

// ---------------------------------------------------------------------------
// K4: MFMA epilogue. out(i,j,o) = bias[o] + sum_k L[i,k]*T[j,o,k]   (bf16 in, f32 out)
// Block = (quadrant, j, 128-i tile); 4 waves, wave = 32 i x 128 o.
// A/B fragments loaded straight from global (1 KB contiguous per wave-load), no LDS.
// XCD-bijective swizzle keeps all i-tiles of a j on one XCD (T[j] L2-resident).
// ---------------------------------------------------------------------------
__global__ __launch_bounds__(256) void epilogue_kernel(
    const float* __restrict__ ws, float* __restrict__ out,
    const float* __restrict__ brr, const float* __restrict__ brl,
    const float* __restrict__ blr, const float* __restrict__ bll)
{
    const unsigned short* wsb = (const unsigned short*)ws;
    int bid = blockIdx.x;
    int wk = (bid & 7) * 576 + (bid >> 3);     // 4608 = 8 * 576, bijective

    const unsigned short *L, *T;
    const float* bias;
    float* ob;
    long istr, jstr;
    int K, j, it;
    if (wk < 2048) {            // rr: rows i (rec), cols j (rec)
        j = wk >> 2; it = wk & 3; K = 32;
        L = wsb + BF_LRR; T = wsb + BF_TRR + (long)j * 4096; bias = brr;
        ob = out; jstr = 128; istr = ROW_STRIDE;
    } else if (wk < 3072) {     // rl: rows i (rec), cols NR+j (lig)
        int w = wk - 2048; j = w >> 2; it = w & 3; K = 32;
        L = wsb + BF_LRL; T = wsb + BF_TRL + (long)j * 4096; bias = brl;
        ob = out + (long)NR * OUT_C; jstr = 128; istr = ROW_STRIDE;
    } else if (wk < 4096) {     // lr: rows NR+j (lig), cols i (rec)
        int w = wk - 3072; j = w >> 2; it = w & 3; K = 32;
        L = wsb + BF_LLR; T = wsb + BF_TLR + (long)j * 4096; bias = blr;
        ob = out + (long)NR * ROW_STRIDE; jstr = ROW_STRIDE; istr = 128;
    } else {                    // ll: rows NR+i, cols NR+j
        int w = wk - 4096; j = w >> 1; it = w & 1; K = 128;
        L = wsb + BF_LLL; T = wsb + BF_TLL + (long)j * 16384; bias = bll;
        ob = out + (long)NR * ROW_STRIDE + (long)NR * OUT_C; jstr = 128; istr = ROW_STRIDE;
    }

    int tid = threadIdx.x;
    int wv = tid >> 6, l = tid & 63;
    int lrow = l & 15, lk = l >> 4;            // A row / k-chunk
    int i0 = it * 128 + wv * 32;

    f32x4 acc[2][8];
    #pragma unroll
    for (int of = 0; of < 8; ++of) {
        float bv = bias[of * 16 + lrow];
        f32x4 t = {bv, bv, bv, bv};
        acc[0][of] = t; acc[1][of] = t;
    }

    int nk = K >> 5;
    for (int ks = 0; ks < nk; ++ks) {
        int kb = ks * 32 + lk * 8;
        bf16x8 a0 = *(const bf16x8*)(L + (long)(i0 + lrow) * K + kb);
        bf16x8 a1 = *(const bf16x8*)(L + (long)(i0 + 16 + lrow) * K + kb);
        #pragma unroll
        for (int of = 0; of < 8; ++of) {
            bf16x8 b = *(const bf16x8*)(T + (long)(of * 16 + lrow) * K + kb);
            acc[0][of] = __builtin_amdgcn_mfma_f32_16x16x32_bf16(a0, b, acc[0][of], 0, 0, 0);
            acc[1][of] = __builtin_amdgcn_mfma_f32_16x16x32_bf16(a1, b, acc[1][of], 0, 0, 0);
        }
    }

    float* obase = ob + (long)j * jstr;
    #pragma unroll
    for (int fi = 0; fi < 2; ++fi)
        #pragma unroll
        for (int of = 0; of < 8; ++of)
            #pragma unroll
            for (int r = 0; r < 4; ++r) {
                int i = i0 + fi * 16 + lk * 4 + r;       // D: row=(l>>4)*4+r, col=l&15
                obase[(long)i * istr + of * 16 + lrow] = acc[fi][of][r];
            }
}

extern "C" void kernel_launch(void* const* d_in, const int* in_sizes, int n_in,
                              void* d_out, int out_size, void* d_ws, size_t ws_size,
                              hipStream_t stream)
{
    (void)in_sizes; (void)n_in; (void)out_size; (void)ws_size;
    const float* rec = (const float*)d_in[0];
    const float* lig = (const float*)d_in[1];
    // d_in[2] = pw_rep: shape-only, never read (all 4 quadrants are overwritten)
    const float* rg  = (const float*)d_in[3];
    const float* rb  = (const float*)d_in[4];
    const float* lg  = (const float*)d_in[5];
    const float* lb  = (const float*)d_in[6];
    const float* Wr  = (const float*)d_in[7];
    const float* br  = (const float*)d_in[8];
    const float* Wl  = (const float*)d_in[9];
    const float* bl  = (const float*)d_in[10];
    const float* Wrr = (const float*)d_in[11];
    const float* brr = (const float*)d_in[12];
    const float* Wrl = (const float*)d_in[13];
    const float* brl = (const float*)d_in[14];
    const float* Wlr = (const float*)d_in[15];
    const float* blr = (const float*)d_in[16];
    const float* Wll = (const float*)d_in[17];
    const float* bll = (const float*)d_in[18];
    float* out = (float*)d_out;
    float* ws  = (float*)d_ws;

    hipLaunchKernelGGL(ln_proj_kernel, dim3(NR + M * NL), dim3(256), 0, stream,
                       rec, lig, rg, rb, lg, lb, Wr, br, Wl, bl, ws);
    hipLaunchKernelGGL(build_t_kernel, dim3(256), dim3(256), 0, stream,
                       Wrr, Wrl, Wlr, Wll, ws);
    hipLaunchKernelGGL(epilogue_kernel, dim3(4608), dim3(256), 0, stream,
                       ws, out, brr, brl, blr, bll);
}